// Round 16
// baseline (257.809 us; speedup 1.0000x reference)
//
#include <hip/hip_runtime.h>
#include <hip/hip_bf16.h>

typedef __attribute__((ext_vector_type(8))) short bfrag_t;
typedef __attribute__((ext_vector_type(4))) short s4_t;
typedef __attribute__((ext_vector_type(4))) float facc_t;
typedef __attribute__((ext_vector_type(16))) float f16acc_t;
typedef __attribute__((ext_vector_type(4))) int i4_t;

#define B_ 4
#define S_ 4096
#define D_ 256

using gas_v = const __attribute__((address_space(1))) void;
using las_v = __attribute__((address_space(3))) void;

__device__ __forceinline__ short f2bf(float f) {
  union { float fv; unsigned u; } x; x.fv = f;
  unsigned r = x.u + 0x7FFFu + ((x.u >> 16) & 1u);
  return (short)(r >> 16);
}

__device__ __forceinline__ int cvtpk(float lo, float hi) {
  int r;
  asm("v_cvt_pk_bf16_f32 %0, %1, %2" : "=v"(r) : "v"(lo), "v"(hi));
  return r;
}

// 2^x via v_exp_f32 (softmax computed in base-2 domain; Q pre-scaled by log2e)
__device__ __forceinline__ float fexp2(float x) {
  float r;
  asm("v_exp_f32 %0, %1" : "=v"(r) : "v"(x));
  return r;
}

__device__ __forceinline__ facc_t mfma16(bfrag_t a, bfrag_t b, facc_t c) {
  return __builtin_amdgcn_mfma_f32_16x16x32_bf16(a, b, c, 0, 0, 0);
}
__device__ __forceinline__ f16acc_t mfma32(bfrag_t a, bfrag_t b, f16acc_t c) {
  return __builtin_amdgcn_mfma_f32_32x32x16_bf16(a, b, c, 0, 0, 0);
}

// ---- transpose weights to bf16 via LDS tiles: WT[p][e][d] = W_p[d][e] ------
__global__ __launch_bounds__(256) void wt_kernel(
    const float* __restrict__ Wq, const float* __restrict__ Wk,
    const float* __restrict__ Wv, short* __restrict__ WT) {
  __shared__ short Tl[256 * 68];
  const int p = blockIdx.x >> 2;
  const int estripe = (blockIdx.x & 3) * 64;
  const float* W = (p == 0) ? Wq : ((p == 1) ? Wk : Wv);
  short* o = WT + p * (D_ * D_);
  const int el = threadIdx.x & 63, dq = threadIdx.x >> 6;
  #pragma unroll 16
  for (int pass = 0; pass < 64; ++pass) {
    int d = pass * 4 + dq;
    Tl[d * 68 + el] = f2bf(W[d * 256 + estripe + el]);
  }
  __syncthreads();
  const int eo = threadIdx.x >> 2, qd = threadIdx.x & 3;
  #pragma unroll
  for (int j = 0; j < 8; ++j) {
    s4_t a, b2;
    #pragma unroll
    for (int t2 = 0; t2 < 4; ++t2) a[t2]  = Tl[(qd * 64 + j * 8 + t2) * 68 + eo];
    #pragma unroll
    for (int t2 = 0; t2 < 4; ++t2) b2[t2] = Tl[(qd * 64 + j * 8 + 4 + t2) * 68 + eo];
    short* dst = o + (estripe + eo) * 256 + qd * 64 + j * 8;
    *reinterpret_cast<s4_t*>(dst) = a;
    *reinterpret_cast<s4_t*>(dst + 4) = b2;
  }
}

// ---- QKV projection: one projection per block (p = bid>>8), LDS-staged -----
__global__ __launch_bounds__(256) void proj_kernel(
    const float* __restrict__ X, const short* __restrict__ WT,
    short* __restrict__ Qb, short* __restrict__ Kb, short* __restrict__ VT) {
  __shared__ __align__(16) short Stg[256 * 72];
  const int tid  = threadIdx.x;
  const int wave = tid >> 6, lane = tid & 63;
  const int lrow = lane & 15, kch = lane >> 4;
  const int p  = blockIdx.x >> 8;
  const int rb = blockIdx.x & 255;
  const int row0 = rb * 64 + wave * 16;
  const int arow = row0 + lrow;
  const int bblk = rb >> 6;

  bfrag_t af[8];
  #pragma unroll
  for (int kt = 0; kt < 8; ++kt) {
    const float* src = X + (size_t)arow * D_ + kt * 32 + kch * 8;
    float4 a = *reinterpret_cast<const float4*>(src);
    float4 b = *reinterpret_cast<const float4*>(src + 4);
    bfrag_t f;
    f[0] = f2bf(a.x); f[1] = f2bf(a.y); f[2] = f2bf(a.z); f[3] = f2bf(a.w);
    f[4] = f2bf(b.x); f[5] = f2bf(b.y); f[6] = f2bf(b.z); f[7] = f2bf(b.w);
    af[kt] = f;
  }

  const short* Wp = WT + p * (D_ * D_);
  facc_t acc[16];
  #pragma unroll
  for (int nt = 0; nt < 16; ++nt) acc[nt] = (facc_t)0.0f;
  #pragma unroll
  for (int kt = 0; kt < 8; ++kt) {
    #pragma unroll
    for (int nt = 0; nt < 16; ++nt) {
      bfrag_t bf = *reinterpret_cast<const bfrag_t*>(
          Wp + (nt * 16 + lrow) * D_ + kt * 32 + kch * 8);
      acc[nt] = mfma16(af[kt], bf, acc[nt]);
    }
  }
  if (p < 2) {
    // Q: 0.0625 * log2(e) = 0.09016844; K: 1.0
    const float sc = (p == 0) ? 0.09016844f : 1.0f;
    #pragma unroll
    for (int nt = 0; nt < 16; ++nt)
      #pragma unroll
      for (int r = 0; r < 4; ++r)
        Stg[(wave * 16 + kch * 4 + r) * 264 + nt * 16 + lrow] =
            f2bf(acc[nt][r] * sc);
    __syncthreads();
    short* dstbase = ((p == 0) ? Qb : Kb) + (size_t)rb * 64 * D_;
    #pragma unroll
    for (int k = 0; k < 8; ++k) {
      int c = k * 256 + tid;
      int row = c >> 5, col = c & 31;
      *reinterpret_cast<bfrag_t*>(dstbase + row * D_ + col * 8) =
          *reinterpret_cast<const bfrag_t*>(&Stg[row * 264 + col * 8]);
    }
  } else {
    #pragma unroll
    for (int nt = 0; nt < 16; ++nt) {
      s4_t v;
      #pragma unroll
      for (int r = 0; r < 4; ++r) v[r] = f2bf(acc[nt][r]);
      *reinterpret_cast<s4_t*>(
          &Stg[(nt * 16 + lrow) * 72 + (wave >> 1) * 32 + (wave & 1) * 16 +
               (kch & 1) * 8 + (kch >> 1) * 4]) = v;
    }
    __syncthreads();
    const int d = tid;
    const int s0 = (rb & 63) * 64;
    short* dst = VT + ((size_t)(bblk * D_ + d)) * S_ + s0;
    #pragma unroll
    for (int j = 0; j < 8; ++j)
      *reinterpret_cast<bfrag_t*>(dst + j * 8) =
          *reinterpret_cast<const bfrag_t*>(&Stg[d * 72 + j * 8]);
  }
}

// ---- flash attention, 32 q/wave via 32x32x16 MFMA, kv-split ----------------
// SPLIT==4: combine fused in-kernel via device-scope semaphore (last arriver).
template<int SPLIT>
__global__ __launch_bounds__(256, 2) void attn32(
    const short* __restrict__ Qb, const short* __restrict__ Kb,
    const short* __restrict__ VT, float* __restrict__ P0,
    float* __restrict__ PX, float2* __restrict__ ML, int* __restrict__ cnt) {
  __shared__ __align__(16) short Kl[2][32 * 256];
  __shared__ __align__(16) short Vl[2][256 * 32];
  const int tid  = threadIdx.x;
  const int wave = tid >> 6, lane = tid & 63;
  const int l31 = lane & 31, hi = lane >> 5;
  const int ksw = (lane & 7) << 4;
  const int vsw = ((l31 >> 1) & 3) << 4;
  const int hw = blockIdx.x;
  const int g = hw & 7, rest = hw >> 3;
  int b, part, qblk;
  if constexpr (SPLIT == 4)      { int combo = ((rest & 1) << 3) | g; b = combo >> 2; part = combo & 3; qblk = rest >> 1; }
  else if constexpr (SPLIT == 2) { b = g >> 1; part = g & 1;          qblk = rest; }
  else                           { b = g >> 1; part = 0;              qblk = (g & 1) * 16 + rest; }
  const int q0 = qblk * 128 + wave * 32;
  const int kvbase = part * (S_ / SPLIT);
  constexpr int STEPS = (S_ / SPLIT) / 32;

  const short* Kbp = Kb + (size_t)b * S_ * D_ + (size_t)kvbase * D_;
  const short* Vbp = VT + (size_t)b * D_ * S_ + kvbase;

  bfrag_t qf[16];
  const short* Qp = Qb + ((size_t)b * S_ + q0 + l31) * D_;
  #pragma unroll
  for (int kt = 0; kt < 16; ++kt)
    qf[kt] = *reinterpret_cast<const bfrag_t*>(Qp + kt * 16 + hi * 8);

  auto stage = [&](int bf, int kv0) {
    #pragma unroll
    for (int j = 0; j < 4; ++j) {           // K 16 KB
      int L = j * 4096 + tid * 16;
      int row = L >> 9;
      int cs = (L & 511) ^ ((row & 7) << 4);
      const short* src = Kbp + (size_t)(kv0 + row) * D_ + (cs >> 1);
      short* dst = &Kl[bf][(j * 4096 + wave * 1024) >> 1];
      __builtin_amdgcn_global_load_lds((gas_v*)src, (las_v*)dst, 16, 0, 0);
    }
    #pragma unroll
    for (int j = 0; j < 4; ++j) {           // V 16 KB
      int L = j * 4096 + tid * 16;
      int d = L >> 6;
      int cs = (L & 63) ^ (((d >> 1) & 3) << 4);
      const short* src = Vbp + (size_t)d * S_ + kv0 + (cs >> 1);
      short* dst = &Vl[bf][(j * 4096 + wave * 1024) >> 1];
      __builtin_amdgcn_global_load_lds((gas_v*)src, (las_v*)dst, 16, 0, 0);
    }
  };

  f16acc_t o32[8];
  #pragma unroll
  for (int nt = 0; nt < 8; ++nt) o32[nt] = (f16acc_t)0.0f;
  float mrow = -3.0e38f, lsum = 0.0f;

  stage(0, 0);
  asm volatile("s_waitcnt vmcnt(0)" ::: "memory");
  __syncthreads();
  int buf = 0;

  #pragma unroll 1
  for (int t = 0; t < STEPS; ++t) {
    if (t < STEPS - 1) stage(buf ^ 1, (t + 1) * 32);
    // ---- S^T = K Q^T : 16 kt of 32x32x16 ----
    f16acc_t s16 = (f16acc_t)0.0f;
    const char* Kbase = (const char*)&Kl[buf][0];
    __builtin_amdgcn_s_setprio(1);
    #pragma unroll
    for (int kt = 0; kt < 16; ++kt) {
      bfrag_t kf = *reinterpret_cast<const bfrag_t*>(
          Kbase + l31 * 512 + ((kt * 32 + hi * 16) ^ ksw));
      s16 = mfma32(kf, qf[kt], s16);
    }
    __builtin_amdgcn_s_setprio(0);
    // ---- softmax (base-2): lane owns q = q0+l31; 16 kv in regs; one shfl ---
    float a0 = fmaxf(fmaxf(s16[0], s16[1]), s16[2]);
    float a1 = fmaxf(fmaxf(s16[3], s16[4]), s16[5]);
    float a2 = fmaxf(fmaxf(s16[6], s16[7]), s16[8]);
    float a3 = fmaxf(fmaxf(s16[9], s16[10]), s16[11]);
    float a4 = fmaxf(fmaxf(s16[12], s16[13]), s16[14]);
    float b0 = fmaxf(fmaxf(a0, a1), a2);
    float b1 = fmaxf(fmaxf(a3, a4), s16[15]);
    float mx = fmaxf(b0, b1);
    mx = fmaxf(mx, __shfl_xor(mx, 32));
    if (mx > mrow + 11.0f) {                // defer-max rescale (2^11 headroom)
      float sf = fexp2(mrow - mx);
      mrow = mx;
      lsum *= sf;
      #pragma unroll
      for (int nt = 0; nt < 8; ++nt) o32[nt] *= sf;
    }
    float pe[16];
    float ls = 0.0f;
    #pragma unroll
    for (int i = 0; i < 16; ++i) {
      pe[i] = fexp2(s16[i] - mrow);
      ls += pe[i];
    }
    lsum += ls;
    i4_t w0, w1;
    w0.x = cvtpk(pe[0], pe[1]);   w0.y = cvtpk(pe[2], pe[3]);
    w0.z = cvtpk(pe[4], pe[5]);   w0.w = cvtpk(pe[6], pe[7]);
    w1.x = cvtpk(pe[8], pe[9]);   w1.y = cvtpk(pe[10], pe[11]);
    w1.z = cvtpk(pe[12], pe[13]); w1.w = cvtpk(pe[14], pe[15]);
    bfrag_t pb0 = __builtin_bit_cast(bfrag_t, w0);
    bfrag_t pb1 = __builtin_bit_cast(bfrag_t, w1);
    // ---- O^T += V^T P^T ----
    const char* Vbase = (const char*)&Vl[buf][0];
    __builtin_amdgcn_s_setprio(1);
    #pragma unroll
    for (int nt = 0; nt < 8; ++nt) {
      const char* vb = Vbase + (nt * 32 + l31) * 64;
      bfrag_t v0 = *reinterpret_cast<const bfrag_t*>(vb + ((hi * 16) ^ vsw));
      o32[nt] = mfma32(v0, pb0, o32[nt]);
      bfrag_t v1 = *reinterpret_cast<const bfrag_t*>(vb + ((32 + hi * 16) ^ vsw));
      o32[nt] = mfma32(v1, pb1, o32[nt]);
    }
    __builtin_amdgcn_s_setprio(0);
    asm volatile("s_waitcnt vmcnt(0)" ::: "memory");
    __syncthreads();
    buf ^= 1;
  }

  // ---- epilogue ----
  lsum += __shfl_xor(lsum, 32);
  float* Pd = (SPLIT == 1 || part == 0)
                  ? P0 : PX + (size_t)(part - 1) * ((size_t)B_ * S_ * D_);
  float* Og = Pd + ((size_t)b * S_ + q0 + l31) * D_;
  if constexpr (SPLIT == 1) {
    float inv = 1.0f / lsum;
    #pragma unroll
    for (int nt = 0; nt < 8; ++nt)
      #pragma unroll
      for (int gg = 0; gg < 4; ++gg) {
        float4 o;
        o.x = o32[nt][gg * 4 + 0] * inv; o.y = o32[nt][gg * 4 + 1] * inv;
        o.z = o32[nt][gg * 4 + 2] * inv; o.w = o32[nt][gg * 4 + 3] * inv;
        *reinterpret_cast<float4*>(Og + nt * 32 + hi * 4 + gg * 8) = o;
      }
  } else {
    #pragma unroll
    for (int nt = 0; nt < 8; ++nt)
      #pragma unroll
      for (int gg = 0; gg < 4; ++gg) {
        float4 o;
        o.x = o32[nt][gg * 4 + 0]; o.y = o32[nt][gg * 4 + 1];
        o.z = o32[nt][gg * 4 + 2]; o.w = o32[nt][gg * 4 + 3];
        *reinterpret_cast<float4*>(Og + nt * 32 + hi * 4 + gg * 8) = o;
      }
    if (lane < 32) {
      float2 ml; ml.x = mrow; ml.y = lsum;  // base-2 domain
      ML[part * (B_ * S_) + b * S_ + q0 + l31] = ml;
    }
  }
  // ---- fused combine (SPLIT==4): last arriver of (b,qblk) merges parts ----
  if constexpr (SPLIT == 4) {
    __threadfence();                        // release: partial + ML visible
    __syncthreads();
    __shared__ int lastS;
    if (tid == 0)
      lastS = (atomicAdd(&cnt[b * 32 + qblk], 1) == SPLIT - 1);
    __syncthreads();
    if (lastS) {
      __threadfence();                      // acquire
      const size_t NPf = (size_t)B_ * S_ * D_;
      #pragma unroll 1
      for (int it = 0; it < 32; ++it) {
        int grow = b * S_ + qblk * 128 + it * 4 + (tid >> 6);
        float2 ml[SPLIT];
        #pragma unroll
        for (int p = 0; p < SPLIT; ++p) ml[p] = ML[p * (B_ * S_) + grow];
        float m = ml[0].x;
        #pragma unroll
        for (int p = 1; p < SPLIT; ++p) m = fmaxf(m, ml[p].x);
        float w[SPLIT];
        float denom = 0.0f;
        #pragma unroll
        for (int p = 0; p < SPLIT; ++p) {
          w[p] = fexp2(ml[p].x - m);
          denom += ml[p].y * w[p];
        }
        float inv = 1.0f / denom;
        size_t idx = (size_t)grow * D_ + (tid & 63) * 4;
        float4 x = *reinterpret_cast<const float4*>(P0 + idx);
        float4 acc;
        acc.x = x.x * w[0]; acc.y = x.y * w[0];
        acc.z = x.z * w[0]; acc.w = x.w * w[0];
        #pragma unroll
        for (int p = 1; p < SPLIT; ++p) {
          float4 y = *reinterpret_cast<const float4*>(
              PX + (size_t)(p - 1) * NPf + idx);
          acc.x += y.x * w[p]; acc.y += y.y * w[p];
          acc.z += y.z * w[p]; acc.w += y.w * w[p];
        }
        acc.x *= inv; acc.y *= inv; acc.z *= inv; acc.w *= inv;
        *reinterpret_cast<float4*>(P0 + idx) = acc;
      }
    }
  }
}

// ---- combine SPLIT kv-part partials (fallback for SPLIT==2) ----------------
template<int SPLIT>
__global__ __launch_bounds__(256) void combineN(
    const float* __restrict__ PX, const float2* __restrict__ ML,
    float* __restrict__ Out) {
  const int r = blockIdx.x * 4 + (threadIdx.x >> 6);
  const int d4 = (threadIdx.x & 63) * 4;
  float2 ml[SPLIT];
  #pragma unroll
  for (int p = 0; p < SPLIT; ++p) ml[p] = ML[p * (B_ * S_) + r];
  float m = ml[0].x;
  #pragma unroll
  for (int p = 1; p < SPLIT; ++p) m = fmaxf(m, ml[p].x);
  float w[SPLIT];
  float denom = 0.0f;
  #pragma unroll
  for (int p = 0; p < SPLIT; ++p) {
    w[p] = fexp2(ml[p].x - m);
    denom += ml[p].y * w[p];
  }
  float inv = 1.0f / denom;
  size_t idx = (size_t)r * D_ + d4;
  float4 x = *reinterpret_cast<float4*>(Out + idx);
  float4 acc;
  acc.x = x.x * w[0]; acc.y = x.y * w[0]; acc.z = x.z * w[0]; acc.w = x.w * w[0];
  #pragma unroll
  for (int p = 1; p < SPLIT; ++p) {
    float4 y = *reinterpret_cast<const float4*>(
        PX + (size_t)(p - 1) * ((size_t)B_ * S_ * D_) + idx);
    acc.x += y.x * w[p]; acc.y += y.y * w[p];
    acc.z += y.z * w[p]; acc.w += y.w * w[p];
  }
  acc.x *= inv; acc.y *= inv; acc.z *= inv; acc.w *= inv;
  *reinterpret_cast<float4*>(Out + idx) = acc;
}

extern "C" void kernel_launch(void* const* d_in, const int* in_sizes, int n_in,
                              void* d_out, int out_size, void* d_ws, size_t ws_size,
                              hipStream_t stream) {
  const float* X  = (const float*)d_in[0];
  const float* Wq = (const float*)d_in[1];
  const float* Wk = (const float*)d_in[2];
  const float* Wv = (const float*)d_in[3];
  float* out = (float*)d_out;

  char* ws = (char*)d_ws;
  short* Qb = (short*)(ws);                       // 8 MB
  short* Kb = (short*)(ws + 8388608);             // 8 MB
  short* VT = (short*)(ws + 16777216);            // 8 MB (V^T, slot-permuted)
  short* WT = (short*)(ws + 25165824);            // 384 KB
  int*   CN = (int*)(ws + 25559040);              // 512 B combine counters
  float2* ML = (float2*)(ws + 25690112);          // 512 KB (m,l per part)
  float* PX  = (float*)(ws + 26214400);           // up to 3 x 16 MB partials
  const size_t NP = (size_t)B_ * S_ * D_ * 4;
  const size_t need4 = 26214400 + 3 * NP;
  const size_t need2 = 26214400 + 1 * NP;

  wt_kernel<<<12, 256, 0, stream>>>(Wq, Wk, Wv, WT);
  proj_kernel<<<768, 256, 0, stream>>>(X, WT, Qb, Kb, VT);
  if (ws_size >= need4) {
    hipMemsetAsync(CN, 0, 512, stream);
    attn32<4><<<512, 256, 0, stream>>>(Qb, Kb, VT, out, PX, ML, CN);
  } else if (ws_size >= need2) {
    attn32<2><<<256, 256, 0, stream>>>(Qb, Kb, VT, out, PX, ML, CN);
    combineN<2><<<(B_ * S_) / 4, 256, 0, stream>>>(PX, ML, out);
  } else {
    attn32<1><<<128, 256, 0, stream>>>(Qb, Kb, VT, out, PX, (float2*)out, CN);
  }
}

// Round 17
// 157.980 us; speedup vs baseline: 1.6319x; 1.6319x over previous
//
#include <hip/hip_runtime.h>
#include <hip/hip_bf16.h>

typedef __attribute__((ext_vector_type(8))) short bfrag_t;
typedef __attribute__((ext_vector_type(4))) short s4_t;
typedef __attribute__((ext_vector_type(4))) float facc_t;
typedef __attribute__((ext_vector_type(16))) float f16acc_t;
typedef __attribute__((ext_vector_type(4))) int i4_t;

#define B_ 4
#define S_ 4096
#define D_ 256

using gas_v = const __attribute__((address_space(1))) void;
using las_v = __attribute__((address_space(3))) void;

__device__ __forceinline__ short f2bf(float f) {
  union { float fv; unsigned u; } x; x.fv = f;
  unsigned r = x.u + 0x7FFFu + ((x.u >> 16) & 1u);
  return (short)(r >> 16);
}

__device__ __forceinline__ int cvtpk(float lo, float hi) {
  int r;
  asm("v_cvt_pk_bf16_f32 %0, %1, %2" : "=v"(r) : "v"(lo), "v"(hi));
  return r;
}

// 2^x via v_exp_f32 (softmax computed in base-2 domain; Q pre-scaled by log2e)
__device__ __forceinline__ float fexp2(float x) {
  float r;
  asm("v_exp_f32 %0, %1" : "=v"(r) : "v"(x));
  return r;
}

__device__ __forceinline__ facc_t mfma16(bfrag_t a, bfrag_t b, facc_t c) {
  return __builtin_amdgcn_mfma_f32_16x16x32_bf16(a, b, c, 0, 0, 0);
}
__device__ __forceinline__ f16acc_t mfma32(bfrag_t a, bfrag_t b, f16acc_t c) {
  return __builtin_amdgcn_mfma_f32_32x32x16_bf16(a, b, c, 0, 0, 0);
}

// ---- transpose weights to bf16 via LDS tiles: WT[p][e][d] = W_p[d][e] ------
__global__ __launch_bounds__(256) void wt_kernel(
    const float* __restrict__ Wq, const float* __restrict__ Wk,
    const float* __restrict__ Wv, short* __restrict__ WT) {
  __shared__ short Tl[256 * 68];
  const int p = blockIdx.x >> 2;
  const int estripe = (blockIdx.x & 3) * 64;
  const float* W = (p == 0) ? Wq : ((p == 1) ? Wk : Wv);
  short* o = WT + p * (D_ * D_);
  const int el = threadIdx.x & 63, dq = threadIdx.x >> 6;
  #pragma unroll 16
  for (int pass = 0; pass < 64; ++pass) {
    int d = pass * 4 + dq;
    Tl[d * 68 + el] = f2bf(W[d * 256 + estripe + el]);
  }
  __syncthreads();
  const int eo = threadIdx.x >> 2, qd = threadIdx.x & 3;
  #pragma unroll
  for (int j = 0; j < 8; ++j) {
    s4_t a, b2;
    #pragma unroll
    for (int t2 = 0; t2 < 4; ++t2) a[t2]  = Tl[(qd * 64 + j * 8 + t2) * 68 + eo];
    #pragma unroll
    for (int t2 = 0; t2 < 4; ++t2) b2[t2] = Tl[(qd * 64 + j * 8 + 4 + t2) * 68 + eo];
    short* dst = o + (estripe + eo) * 256 + qd * 64 + j * 8;
    *reinterpret_cast<s4_t*>(dst) = a;
    *reinterpret_cast<s4_t*>(dst + 4) = b2;
  }
}

// ---- QKV projection: one projection per block (p = bid>>8), LDS-staged -----
// Q pre-scaled by (1/sqrt(256)) * log2(e) for base-2 softmax.
// V stored transposed + slot-permuted per 32-kv group:
//   kv_local = wave*16+kch*4+r -> col (wave>>1)*32+(wave&1)*16+(kch&1)*8+(kch>>1)*4+r
__global__ __launch_bounds__(256) void proj_kernel(
    const float* __restrict__ X, const short* __restrict__ WT,
    short* __restrict__ Qb, short* __restrict__ Kb, short* __restrict__ VT) {
  __shared__ __align__(16) short Stg[256 * 72];
  const int tid  = threadIdx.x;
  const int wave = tid >> 6, lane = tid & 63;
  const int lrow = lane & 15, kch = lane >> 4;
  const int p  = blockIdx.x >> 8;
  const int rb = blockIdx.x & 255;
  const int row0 = rb * 64 + wave * 16;
  const int arow = row0 + lrow;
  const int bblk = rb >> 6;

  bfrag_t af[8];
  #pragma unroll
  for (int kt = 0; kt < 8; ++kt) {
    const float* src = X + (size_t)arow * D_ + kt * 32 + kch * 8;
    float4 a = *reinterpret_cast<const float4*>(src);
    float4 b = *reinterpret_cast<const float4*>(src + 4);
    bfrag_t f;
    f[0] = f2bf(a.x); f[1] = f2bf(a.y); f[2] = f2bf(a.z); f[3] = f2bf(a.w);
    f[4] = f2bf(b.x); f[5] = f2bf(b.y); f[6] = f2bf(b.z); f[7] = f2bf(b.w);
    af[kt] = f;
  }

  const short* Wp = WT + p * (D_ * D_);
  facc_t acc[16];
  #pragma unroll
  for (int nt = 0; nt < 16; ++nt) acc[nt] = (facc_t)0.0f;
  #pragma unroll
  for (int kt = 0; kt < 8; ++kt) {
    #pragma unroll
    for (int nt = 0; nt < 16; ++nt) {
      bfrag_t bf = *reinterpret_cast<const bfrag_t*>(
          Wp + (nt * 16 + lrow) * D_ + kt * 32 + kch * 8);
      acc[nt] = mfma16(af[kt], bf, acc[nt]);
    }
  }
  if (p < 2) {
    // Q: 0.0625 * log2(e) = 0.09016844; K: 1.0
    const float sc = (p == 0) ? 0.09016844f : 1.0f;
    #pragma unroll
    for (int nt = 0; nt < 16; ++nt)
      #pragma unroll
      for (int r = 0; r < 4; ++r)
        Stg[(wave * 16 + kch * 4 + r) * 264 + nt * 16 + lrow] =
            f2bf(acc[nt][r] * sc);
    __syncthreads();
    short* dstbase = ((p == 0) ? Qb : Kb) + (size_t)rb * 64 * D_;
    #pragma unroll
    for (int k = 0; k < 8; ++k) {
      int c = k * 256 + tid;
      int row = c >> 5, col = c & 31;
      *reinterpret_cast<bfrag_t*>(dstbase + row * D_ + col * 8) =
          *reinterpret_cast<const bfrag_t*>(&Stg[row * 264 + col * 8]);
    }
  } else {
    #pragma unroll
    for (int nt = 0; nt < 16; ++nt) {
      s4_t v;
      #pragma unroll
      for (int r = 0; r < 4; ++r) v[r] = f2bf(acc[nt][r]);
      *reinterpret_cast<s4_t*>(
          &Stg[(nt * 16 + lrow) * 72 + (wave >> 1) * 32 + (wave & 1) * 16 +
               (kch & 1) * 8 + (kch >> 1) * 4]) = v;
    }
    __syncthreads();
    const int d = tid;
    const int s0 = (rb & 63) * 64;
    short* dst = VT + ((size_t)(bblk * D_ + d)) * S_ + s0;
    #pragma unroll
    for (int j = 0; j < 8; ++j)
      *reinterpret_cast<bfrag_t*>(dst + j * 8) =
          *reinterpret_cast<const bfrag_t*>(&Stg[d * 72 + j * 8]);
  }
}

// ---- flash attention, 32 q/wave via 32x32x16 MFMA, kv-split template -------
// Swapped QK^T: S^T col=lane&31=q, row=kv=(reg&3)+8*(reg>>2)+4*hi.
// Base-2 online softmax (Q pre-scaled by log2e). P regs feed PV B directly.
template<int SPLIT>
__global__ __launch_bounds__(256, 2) void attn32(
    const short* __restrict__ Qb, const short* __restrict__ Kb,
    const short* __restrict__ VT, float* __restrict__ P0,
    float* __restrict__ PX, float2* __restrict__ ML) {
  // K tile [32 kv][256 d] (512B rows, byte ^= (kv&7)<<4)
  // V tile [256 d][32 slots] (64B rows, byte ^= ((d>>1)&3)<<4)
  __shared__ __align__(16) short Kl[2][32 * 256];
  __shared__ __align__(16) short Vl[2][256 * 32];
  const int tid  = threadIdx.x;
  const int wave = tid >> 6, lane = tid & 63;
  const int l31 = lane & 31, hi = lane >> 5;
  const int ksw = (lane & 7) << 4;
  const int vsw = ((l31 >> 1) & 3) << 4;
  const int hw = blockIdx.x;
  const int g = hw & 7, rest = hw >> 3;
  int b, part, qblk;
  if constexpr (SPLIT == 4)      { b = g >> 1; part = (g & 1) * 2 + (rest & 1); qblk = rest >> 1; }
  else if constexpr (SPLIT == 2) { b = g >> 1; part = g & 1;                    qblk = rest; }
  else                           { b = g >> 1; part = 0;                qblk = (g & 1) * 16 + rest; }
  const int q0 = qblk * 128 + wave * 32;
  const int kvbase = part * (S_ / SPLIT);
  constexpr int STEPS = (S_ / SPLIT) / 32;

  const short* Kbp = Kb + (size_t)b * S_ * D_ + (size_t)kvbase * D_;
  const short* Vbp = VT + (size_t)b * D_ * S_ + kvbase;

  // Q as B-operand: col = l31 (q), k-slot hi*8+e -> d = kt*16 + hi*8 + e
  bfrag_t qf[16];
  const short* Qp = Qb + ((size_t)b * S_ + q0 + l31) * D_;
  #pragma unroll
  for (int kt = 0; kt < 16; ++kt)
    qf[kt] = *reinterpret_cast<const bfrag_t*>(Qp + kt * 16 + hi * 8);

  auto stage = [&](int bf, int kv0) {
    #pragma unroll
    for (int j = 0; j < 4; ++j) {           // K 16 KB
      int L = j * 4096 + tid * 16;
      int row = L >> 9;
      int cs = (L & 511) ^ ((row & 7) << 4);
      const short* src = Kbp + (size_t)(kv0 + row) * D_ + (cs >> 1);
      short* dst = &Kl[bf][(j * 4096 + wave * 1024) >> 1];
      __builtin_amdgcn_global_load_lds((gas_v*)src, (las_v*)dst, 16, 0, 0);
    }
    #pragma unroll
    for (int j = 0; j < 4; ++j) {           // V 16 KB
      int L = j * 4096 + tid * 16;
      int d = L >> 6;
      int cs = (L & 63) ^ (((d >> 1) & 3) << 4);
      const short* src = Vbp + (size_t)d * S_ + kv0 + (cs >> 1);
      short* dst = &Vl[bf][(j * 4096 + wave * 1024) >> 1];
      __builtin_amdgcn_global_load_lds((gas_v*)src, (las_v*)dst, 16, 0, 0);
    }
  };

  f16acc_t o32[8];
  #pragma unroll
  for (int nt = 0; nt < 8; ++nt) o32[nt] = (f16acc_t)0.0f;
  float mrow = -3.0e38f, lsum = 0.0f;

  stage(0, 0);
  asm volatile("s_waitcnt vmcnt(0)" ::: "memory");
  __syncthreads();
  int buf = 0;

  #pragma unroll 1
  for (int t = 0; t < STEPS; ++t) {
    if (t < STEPS - 1) stage(buf ^ 1, (t + 1) * 32);
    // ---- S^T = K Q^T : 16 kt of 32x32x16 ----
    f16acc_t s16 = (f16acc_t)0.0f;
    const char* Kbase = (const char*)&Kl[buf][0];
    __builtin_amdgcn_s_setprio(1);
    #pragma unroll
    for (int kt = 0; kt < 16; ++kt) {
      bfrag_t kf = *reinterpret_cast<const bfrag_t*>(
          Kbase + l31 * 512 + ((kt * 32 + hi * 16) ^ ksw));
      s16 = mfma32(kf, qf[kt], s16);
    }
    __builtin_amdgcn_s_setprio(0);
    // ---- softmax (base-2): lane owns q = q0+l31; 16 kv in regs; one shfl ---
    float a0 = fmaxf(fmaxf(s16[0], s16[1]), s16[2]);
    float a1 = fmaxf(fmaxf(s16[3], s16[4]), s16[5]);
    float a2 = fmaxf(fmaxf(s16[6], s16[7]), s16[8]);
    float a3 = fmaxf(fmaxf(s16[9], s16[10]), s16[11]);
    float a4 = fmaxf(fmaxf(s16[12], s16[13]), s16[14]);
    float b0 = fmaxf(fmaxf(a0, a1), a2);
    float b1 = fmaxf(fmaxf(a3, a4), s16[15]);
    float mx = fmaxf(b0, b1);
    mx = fmaxf(mx, __shfl_xor(mx, 32));
    if (mx > mrow + 11.0f) {                // defer-max rescale (2^11 headroom)
      float sf = fexp2(mrow - mx);
      mrow = mx;
      lsum *= sf;
      #pragma unroll
      for (int nt = 0; nt < 8; ++nt) o32[nt] *= sf;
    }
    float pe[16];
    float ls = 0.0f;
    #pragma unroll
    for (int i = 0; i < 16; ++i) {
      pe[i] = fexp2(s16[i] - mrow);
      ls += pe[i];
    }
    lsum += ls;
    // ---- P -> bf16 B-frags (register-order; cvt_pk pairs) ----
    i4_t w0, w1;
    w0.x = cvtpk(pe[0], pe[1]);   w0.y = cvtpk(pe[2], pe[3]);
    w0.z = cvtpk(pe[4], pe[5]);   w0.w = cvtpk(pe[6], pe[7]);
    w1.x = cvtpk(pe[8], pe[9]);   w1.y = cvtpk(pe[10], pe[11]);
    w1.z = cvtpk(pe[12], pe[13]); w1.w = cvtpk(pe[14], pe[15]);
    bfrag_t pb0 = __builtin_bit_cast(bfrag_t, w0);
    bfrag_t pb1 = __builtin_bit_cast(bfrag_t, w1);
    // ---- O^T += V^T P^T : 8 d-blocks x 2 ----
    const char* Vbase = (const char*)&Vl[buf][0];
    __builtin_amdgcn_s_setprio(1);
    #pragma unroll
    for (int nt = 0; nt < 8; ++nt) {
      const char* vb = Vbase + (nt * 32 + l31) * 64;
      bfrag_t v0 = *reinterpret_cast<const bfrag_t*>(vb + ((hi * 16) ^ vsw));
      o32[nt] = mfma32(v0, pb0, o32[nt]);
      bfrag_t v1 = *reinterpret_cast<const bfrag_t*>(vb + ((32 + hi * 16) ^ vsw));
      o32[nt] = mfma32(v1, pb1, o32[nt]);
    }
    __builtin_amdgcn_s_setprio(0);
    asm volatile("s_waitcnt vmcnt(0)" ::: "memory");
    __syncthreads();
    buf ^= 1;
  }

  // ---- epilogue ----
  lsum += __shfl_xor(lsum, 32);
  float* Pd = (SPLIT == 1 || part == 0)
                  ? P0 : PX + (size_t)(part - 1) * ((size_t)B_ * S_ * D_);
  float* Og = Pd + ((size_t)b * S_ + q0 + l31) * D_;
  if constexpr (SPLIT == 1) {
    float inv = 1.0f / lsum;
    #pragma unroll
    for (int nt = 0; nt < 8; ++nt)
      #pragma unroll
      for (int gg = 0; gg < 4; ++gg) {
        float4 o;
        o.x = o32[nt][gg * 4 + 0] * inv; o.y = o32[nt][gg * 4 + 1] * inv;
        o.z = o32[nt][gg * 4 + 2] * inv; o.w = o32[nt][gg * 4 + 3] * inv;
        *reinterpret_cast<float4*>(Og + nt * 32 + hi * 4 + gg * 8) = o;
      }
  } else {
    #pragma unroll
    for (int nt = 0; nt < 8; ++nt)
      #pragma unroll
      for (int gg = 0; gg < 4; ++gg) {
        float4 o;
        o.x = o32[nt][gg * 4 + 0]; o.y = o32[nt][gg * 4 + 1];
        o.z = o32[nt][gg * 4 + 2]; o.w = o32[nt][gg * 4 + 3];
        *reinterpret_cast<float4*>(Og + nt * 32 + hi * 4 + gg * 8) = o;
      }
    if (lane < 32) {
      float2 ml; ml.x = mrow; ml.y = lsum;  // base-2 domain
      ML[part * (B_ * S_) + b * S_ + q0 + l31] = ml;
    }
  }
}

// ---- combine SPLIT kv-part partials (base-2 weights) -----------------------
template<int SPLIT>
__global__ __launch_bounds__(256) void combineN(
    const float* __restrict__ PX, const float2* __restrict__ ML,
    float* __restrict__ Out) {
  const int r = blockIdx.x * 4 + (threadIdx.x >> 6);
  const int d4 = (threadIdx.x & 63) * 4;
  float2 ml[SPLIT];
  #pragma unroll
  for (int p = 0; p < SPLIT; ++p) ml[p] = ML[p * (B_ * S_) + r];
  float m = ml[0].x;
  #pragma unroll
  for (int p = 1; p < SPLIT; ++p) m = fmaxf(m, ml[p].x);
  float w[SPLIT];
  float denom = 0.0f;
  #pragma unroll
  for (int p = 0; p < SPLIT; ++p) {
    w[p] = fexp2(ml[p].x - m);
    denom += ml[p].y * w[p];
  }
  float inv = 1.0f / denom;
  size_t idx = (size_t)r * D_ + d4;
  float4 x = *reinterpret_cast<float4*>(Out + idx);
  float4 acc;
  acc.x = x.x * w[0]; acc.y = x.y * w[0]; acc.z = x.z * w[0]; acc.w = x.w * w[0];
  #pragma unroll
  for (int p = 1; p < SPLIT; ++p) {
    float4 y = *reinterpret_cast<const float4*>(
        PX + (size_t)(p - 1) * ((size_t)B_ * S_ * D_) + idx);
    acc.x += y.x * w[p]; acc.y += y.y * w[p];
    acc.z += y.z * w[p]; acc.w += y.w * w[p];
  }
  acc.x *= inv; acc.y *= inv; acc.z *= inv; acc.w *= inv;
  *reinterpret_cast<float4*>(Out + idx) = acc;
}

extern "C" void kernel_launch(void* const* d_in, const int* in_sizes, int n_in,
                              void* d_out, int out_size, void* d_ws, size_t ws_size,
                              hipStream_t stream) {
  const float* X  = (const float*)d_in[0];
  const float* Wq = (const float*)d_in[1];
  const float* Wk = (const float*)d_in[2];
  const float* Wv = (const float*)d_in[3];
  float* out = (float*)d_out;

  char* ws = (char*)d_ws;
  short* Qb = (short*)(ws);                       // 8 MB
  short* Kb = (short*)(ws + 8388608);             // 8 MB
  short* VT = (short*)(ws + 16777216);            // 8 MB (V^T, slot-permuted)
  short* WT = (short*)(ws + 25165824);            // 384 KB
  float2* ML = (float2*)(ws + 25690112);          // 512 KB (m,l per part)
  float* PX  = (float*)(ws + 26214400);           // up to 3 x 16 MB partials
  const size_t NP = (size_t)B_ * S_ * D_ * 4;
  const size_t need4 = 26214400 + 3 * NP;
  const size_t need2 = 26214400 + 1 * NP;

  wt_kernel<<<12, 256, 0, stream>>>(Wq, Wk, Wv, WT);
  proj_kernel<<<768, 256, 0, stream>>>(X, WT, Qb, Kb, VT);
  if (ws_size >= need4) {
    attn32<4><<<512, 256, 0, stream>>>(Qb, Kb, VT, out, PX, ML);
    combineN<4><<<(B_ * S_) / 4, 256, 0, stream>>>(PX, ML, out);
  } else if (ws_size >= need2) {
    attn32<2><<<256, 256, 0, stream>>>(Qb, Kb, VT, out, PX, ML);
    combineN<2><<<(B_ * S_) / 4, 256, 0, stream>>>(PX, ML, out);
  } else {
    attn32<1><<<128, 256, 0, stream>>>(Qb, Kb, VT, out, PX, (float2*)out);
  }
}

// Round 18
// 156.033 us; speedup vs baseline: 1.6523x; 1.0125x over previous
//
#include <hip/hip_runtime.h>
#include <hip/hip_bf16.h>
#include <hip/hip_fp16.h>

typedef __attribute__((ext_vector_type(8))) short bfrag_t;
typedef __attribute__((ext_vector_type(4))) short s4_t;
typedef __attribute__((ext_vector_type(4))) float facc_t;
typedef __attribute__((ext_vector_type(16))) float f16acc_t;
typedef __attribute__((ext_vector_type(4))) int i4_t;

#define B_ 4
#define S_ 4096
#define D_ 256

using gas_v = const __attribute__((address_space(1))) void;
using las_v = __attribute__((address_space(3))) void;

__device__ __forceinline__ short f2bf(float f) {
  union { float fv; unsigned u; } x; x.fv = f;
  unsigned r = x.u + 0x7FFFu + ((x.u >> 16) & 1u);
  return (short)(r >> 16);
}

__device__ __forceinline__ int cvtpk(float lo, float hi) {
  int r;
  asm("v_cvt_pk_bf16_f32 %0, %1, %2" : "=v"(r) : "v"(lo), "v"(hi));
  return r;
}

// pack 2 f32 -> 2 f16 (RTZ)
__device__ __forceinline__ int cvtpk_f16(float lo, float hi) {
  int r;
  asm("v_cvt_pkrtz_f16_f32 %0, %1, %2" : "=v"(r) : "v"(lo), "v"(hi));
  return r;
}

// 2^x via v_exp_f32 (softmax computed in base-2 domain; Q pre-scaled by log2e)
__device__ __forceinline__ float fexp2(float x) {
  float r;
  asm("v_exp_f32 %0, %1" : "=v"(r) : "v"(x));
  return r;
}

__device__ __forceinline__ facc_t mfma16(bfrag_t a, bfrag_t b, facc_t c) {
  return __builtin_amdgcn_mfma_f32_16x16x32_bf16(a, b, c, 0, 0, 0);
}
__device__ __forceinline__ f16acc_t mfma32(bfrag_t a, bfrag_t b, f16acc_t c) {
  return __builtin_amdgcn_mfma_f32_32x32x16_bf16(a, b, c, 0, 0, 0);
}

// ---- transpose weights to bf16 via LDS tiles: WT[p][e][d] = W_p[d][e] ------
__global__ __launch_bounds__(256) void wt_kernel(
    const float* __restrict__ Wq, const float* __restrict__ Wk,
    const float* __restrict__ Wv, short* __restrict__ WT) {
  __shared__ short Tl[256 * 68];
  const int p = blockIdx.x >> 2;
  const int estripe = (blockIdx.x & 3) * 64;
  const float* W = (p == 0) ? Wq : ((p == 1) ? Wk : Wv);
  short* o = WT + p * (D_ * D_);
  const int el = threadIdx.x & 63, dq = threadIdx.x >> 6;
  #pragma unroll 16
  for (int pass = 0; pass < 64; ++pass) {
    int d = pass * 4 + dq;
    Tl[d * 68 + el] = f2bf(W[d * 256 + estripe + el]);
  }
  __syncthreads();
  const int eo = threadIdx.x >> 2, qd = threadIdx.x & 3;
  #pragma unroll
  for (int j = 0; j < 8; ++j) {
    s4_t a, b2;
    #pragma unroll
    for (int t2 = 0; t2 < 4; ++t2) a[t2]  = Tl[(qd * 64 + j * 8 + t2) * 68 + eo];
    #pragma unroll
    for (int t2 = 0; t2 < 4; ++t2) b2[t2] = Tl[(qd * 64 + j * 8 + 4 + t2) * 68 + eo];
    short* dst = o + (estripe + eo) * 256 + qd * 64 + j * 8;
    *reinterpret_cast<s4_t*>(dst) = a;
    *reinterpret_cast<s4_t*>(dst + 4) = b2;
  }
}

// ---- QKV projection: one projection per block (p = bid>>8), LDS-staged -----
__global__ __launch_bounds__(256) void proj_kernel(
    const float* __restrict__ X, const short* __restrict__ WT,
    short* __restrict__ Qb, short* __restrict__ Kb, short* __restrict__ VT) {
  __shared__ __align__(16) short Stg[256 * 72];
  const int tid  = threadIdx.x;
  const int wave = tid >> 6, lane = tid & 63;
  const int lrow = lane & 15, kch = lane >> 4;
  const int p  = blockIdx.x >> 8;
  const int rb = blockIdx.x & 255;
  const int row0 = rb * 64 + wave * 16;
  const int arow = row0 + lrow;
  const int bblk = rb >> 6;

  bfrag_t af[8];
  #pragma unroll
  for (int kt = 0; kt < 8; ++kt) {
    const float* src = X + (size_t)arow * D_ + kt * 32 + kch * 8;
    float4 a = *reinterpret_cast<const float4*>(src);
    float4 b = *reinterpret_cast<const float4*>(src + 4);
    bfrag_t f;
    f[0] = f2bf(a.x); f[1] = f2bf(a.y); f[2] = f2bf(a.z); f[3] = f2bf(a.w);
    f[4] = f2bf(b.x); f[5] = f2bf(b.y); f[6] = f2bf(b.z); f[7] = f2bf(b.w);
    af[kt] = f;
  }

  const short* Wp = WT + p * (D_ * D_);
  facc_t acc[16];
  #pragma unroll
  for (int nt = 0; nt < 16; ++nt) acc[nt] = (facc_t)0.0f;
  #pragma unroll
  for (int kt = 0; kt < 8; ++kt) {
    #pragma unroll
    for (int nt = 0; nt < 16; ++nt) {
      bfrag_t bf = *reinterpret_cast<const bfrag_t*>(
          Wp + (nt * 16 + lrow) * D_ + kt * 32 + kch * 8);
      acc[nt] = mfma16(af[kt], bf, acc[nt]);
    }
  }
  if (p < 2) {
    // Q: 0.0625 * log2(e) = 0.09016844; K: 1.0
    const float sc = (p == 0) ? 0.09016844f : 1.0f;
    #pragma unroll
    for (int nt = 0; nt < 16; ++nt)
      #pragma unroll
      for (int r = 0; r < 4; ++r)
        Stg[(wave * 16 + kch * 4 + r) * 264 + nt * 16 + lrow] =
            f2bf(acc[nt][r] * sc);
    __syncthreads();
    short* dstbase = ((p == 0) ? Qb : Kb) + (size_t)rb * 64 * D_;
    #pragma unroll
    for (int k = 0; k < 8; ++k) {
      int c = k * 256 + tid;
      int row = c >> 5, col = c & 31;
      *reinterpret_cast<bfrag_t*>(dstbase + row * D_ + col * 8) =
          *reinterpret_cast<const bfrag_t*>(&Stg[row * 264 + col * 8]);
    }
  } else {
    #pragma unroll
    for (int nt = 0; nt < 16; ++nt) {
      s4_t v;
      #pragma unroll
      for (int r = 0; r < 4; ++r) v[r] = f2bf(acc[nt][r]);
      *reinterpret_cast<s4_t*>(
          &Stg[(nt * 16 + lrow) * 72 + (wave >> 1) * 32 + (wave & 1) * 16 +
               (kch & 1) * 8 + (kch >> 1) * 4]) = v;
    }
    __syncthreads();
    const int d = tid;
    const int s0 = (rb & 63) * 64;
    short* dst = VT + ((size_t)(bblk * D_ + d)) * S_ + s0;
    #pragma unroll
    for (int j = 0; j < 8; ++j)
      *reinterpret_cast<bfrag_t*>(dst + j * 8) =
          *reinterpret_cast<const bfrag_t*>(&Stg[d * 72 + j * 8]);
  }
}

// ---- flash attention, 32 q/wave via 32x32x16 MFMA, kv-split template -------
// SPLIT>=2: partials stored NORMALIZED (O/l) in fp16; ML holds (m, l) base-2.
template<int SPLIT>
__global__ __launch_bounds__(256, 2) void attn32(
    const short* __restrict__ Qb, const short* __restrict__ Kb,
    const short* __restrict__ VT, float* __restrict__ P0,
    __half* __restrict__ PH, float2* __restrict__ ML) {
  __shared__ __align__(16) short Kl[2][32 * 256];
  __shared__ __align__(16) short Vl[2][256 * 32];
  const int tid  = threadIdx.x;
  const int wave = tid >> 6, lane = tid & 63;
  const int l31 = lane & 31, hi = lane >> 5;
  const int ksw = (lane & 7) << 4;
  const int vsw = ((l31 >> 1) & 3) << 4;
  const int hw = blockIdx.x;
  const int g = hw & 7, rest = hw >> 3;
  int b, part, qblk;
  if constexpr (SPLIT == 4)      { b = g >> 1; part = (g & 1) * 2 + (rest & 1); qblk = rest >> 1; }
  else if constexpr (SPLIT == 2) { b = g >> 1; part = g & 1;                    qblk = rest; }
  else                           { b = g >> 1; part = 0;                qblk = (g & 1) * 16 + rest; }
  const int q0 = qblk * 128 + wave * 32;
  const int kvbase = part * (S_ / SPLIT);
  constexpr int STEPS = (S_ / SPLIT) / 32;

  const short* Kbp = Kb + (size_t)b * S_ * D_ + (size_t)kvbase * D_;
  const short* Vbp = VT + (size_t)b * D_ * S_ + kvbase;

  bfrag_t qf[16];
  const short* Qp = Qb + ((size_t)b * S_ + q0 + l31) * D_;
  #pragma unroll
  for (int kt = 0; kt < 16; ++kt)
    qf[kt] = *reinterpret_cast<const bfrag_t*>(Qp + kt * 16 + hi * 8);

  auto stage = [&](int bf, int kv0) {
    #pragma unroll
    for (int j = 0; j < 4; ++j) {           // K 16 KB
      int L = j * 4096 + tid * 16;
      int row = L >> 9;
      int cs = (L & 511) ^ ((row & 7) << 4);
      const short* src = Kbp + (size_t)(kv0 + row) * D_ + (cs >> 1);
      short* dst = &Kl[bf][(j * 4096 + wave * 1024) >> 1];
      __builtin_amdgcn_global_load_lds((gas_v*)src, (las_v*)dst, 16, 0, 0);
    }
    #pragma unroll
    for (int j = 0; j < 4; ++j) {           // V 16 KB
      int L = j * 4096 + tid * 16;
      int d = L >> 6;
      int cs = (L & 63) ^ (((d >> 1) & 3) << 4);
      const short* src = Vbp + (size_t)d * S_ + kv0 + (cs >> 1);
      short* dst = &Vl[bf][(j * 4096 + wave * 1024) >> 1];
      __builtin_amdgcn_global_load_lds((gas_v*)src, (las_v*)dst, 16, 0, 0);
    }
  };

  f16acc_t o32[8];
  #pragma unroll
  for (int nt = 0; nt < 8; ++nt) o32[nt] = (f16acc_t)0.0f;
  float mrow = -3.0e38f, lsum = 0.0f;

  stage(0, 0);
  asm volatile("s_waitcnt vmcnt(0)" ::: "memory");
  __syncthreads();
  int buf = 0;

  #pragma unroll 1
  for (int t = 0; t < STEPS; ++t) {
    if (t < STEPS - 1) stage(buf ^ 1, (t + 1) * 32);
    // ---- S^T = K Q^T : 16 kt of 32x32x16 ----
    f16acc_t s16 = (f16acc_t)0.0f;
    const char* Kbase = (const char*)&Kl[buf][0];
    __builtin_amdgcn_s_setprio(1);
    #pragma unroll
    for (int kt = 0; kt < 16; ++kt) {
      bfrag_t kf = *reinterpret_cast<const bfrag_t*>(
          Kbase + l31 * 512 + ((kt * 32 + hi * 16) ^ ksw));
      s16 = mfma32(kf, qf[kt], s16);
    }
    __builtin_amdgcn_s_setprio(0);
    // ---- softmax (base-2): lane owns q = q0+l31; 16 kv in regs; one shfl ---
    float a0 = fmaxf(fmaxf(s16[0], s16[1]), s16[2]);
    float a1 = fmaxf(fmaxf(s16[3], s16[4]), s16[5]);
    float a2 = fmaxf(fmaxf(s16[6], s16[7]), s16[8]);
    float a3 = fmaxf(fmaxf(s16[9], s16[10]), s16[11]);
    float a4 = fmaxf(fmaxf(s16[12], s16[13]), s16[14]);
    float b0 = fmaxf(fmaxf(a0, a1), a2);
    float b1 = fmaxf(fmaxf(a3, a4), s16[15]);
    float mx = fmaxf(b0, b1);
    mx = fmaxf(mx, __shfl_xor(mx, 32));
    if (mx > mrow + 11.0f) {                // defer-max rescale (2^11 headroom)
      float sf = fexp2(mrow - mx);
      mrow = mx;
      lsum *= sf;
      #pragma unroll
      for (int nt = 0; nt < 8; ++nt) o32[nt] *= sf;
    }
    float pe[16];
    float ls = 0.0f;
    #pragma unroll
    for (int i = 0; i < 16; ++i) {
      pe[i] = fexp2(s16[i] - mrow);
      ls += pe[i];
    }
    lsum += ls;
    // ---- P -> bf16 B-frags (register-order; cvt_pk pairs) ----
    i4_t w0, w1;
    w0.x = cvtpk(pe[0], pe[1]);   w0.y = cvtpk(pe[2], pe[3]);
    w0.z = cvtpk(pe[4], pe[5]);   w0.w = cvtpk(pe[6], pe[7]);
    w1.x = cvtpk(pe[8], pe[9]);   w1.y = cvtpk(pe[10], pe[11]);
    w1.z = cvtpk(pe[12], pe[13]); w1.w = cvtpk(pe[14], pe[15]);
    bfrag_t pb0 = __builtin_bit_cast(bfrag_t, w0);
    bfrag_t pb1 = __builtin_bit_cast(bfrag_t, w1);
    // ---- O^T += V^T P^T : 8 d-blocks x 2 ----
    const char* Vbase = (const char*)&Vl[buf][0];
    __builtin_amdgcn_s_setprio(1);
    #pragma unroll
    for (int nt = 0; nt < 8; ++nt) {
      const char* vb = Vbase + (nt * 32 + l31) * 64;
      bfrag_t v0 = *reinterpret_cast<const bfrag_t*>(vb + ((hi * 16) ^ vsw));
      o32[nt] = mfma32(v0, pb0, o32[nt]);
      bfrag_t v1 = *reinterpret_cast<const bfrag_t*>(vb + ((32 + hi * 16) ^ vsw));
      o32[nt] = mfma32(v1, pb1, o32[nt]);
    }
    __builtin_amdgcn_s_setprio(0);
    asm volatile("s_waitcnt vmcnt(0)" ::: "memory");
    __syncthreads();
    buf ^= 1;
  }

  // ---- epilogue ----
  lsum += __shfl_xor(lsum, 32);
  float inv = 1.0f / lsum;
  if constexpr (SPLIT == 1) {
    float* Og = P0 + ((size_t)b * S_ + q0 + l31) * D_;
    #pragma unroll
    for (int nt = 0; nt < 8; ++nt)
      #pragma unroll
      for (int gg = 0; gg < 4; ++gg) {
        float4 o;
        o.x = o32[nt][gg * 4 + 0] * inv; o.y = o32[nt][gg * 4 + 1] * inv;
        o.z = o32[nt][gg * 4 + 2] * inv; o.w = o32[nt][gg * 4 + 3] * inv;
        *reinterpret_cast<float4*>(Og + nt * 32 + hi * 4 + gg * 8) = o;
      }
  } else {
    // normalized fp16 partial: PH[part][row][d]
    __half* Ph = PH + (size_t)part * ((size_t)B_ * S_ * D_) +
                 ((size_t)b * S_ + q0 + l31) * D_;
    #pragma unroll
    for (int nt = 0; nt < 8; ++nt)
      #pragma unroll
      for (int gg = 0; gg < 4; ++gg) {
        int2 hp;
        hp.x = cvtpk_f16(o32[nt][gg * 4 + 0] * inv, o32[nt][gg * 4 + 1] * inv);
        hp.y = cvtpk_f16(o32[nt][gg * 4 + 2] * inv, o32[nt][gg * 4 + 3] * inv);
        *reinterpret_cast<int2*>(Ph + nt * 32 + hi * 4 + gg * 8) = hp;
      }
    if (lane < 32) {
      float2 ml; ml.x = mrow; ml.y = lsum;  // base-2 domain
      ML[part * (B_ * S_) + b * S_ + q0 + l31] = ml;
    }
  }
}

// ---- combine SPLIT normalized fp16 partials (weights = 2^(m_p-m) * l_p) ----
template<int SPLIT>
__global__ __launch_bounds__(256) void combineN(
    const __half* __restrict__ PH, const float2* __restrict__ ML,
    float* __restrict__ Out) {
  const int r = blockIdx.x * 4 + (threadIdx.x >> 6);
  const int d4 = (threadIdx.x & 63) * 4;
  const size_t NPf = (size_t)B_ * S_ * D_;
  float2 ml[SPLIT];
  #pragma unroll
  for (int p = 0; p < SPLIT; ++p) ml[p] = ML[p * (B_ * S_) + r];
  float m = ml[0].x;
  #pragma unroll
  for (int p = 1; p < SPLIT; ++p) m = fmaxf(m, ml[p].x);
  float w[SPLIT];
  float denom = 0.0f;
  #pragma unroll
  for (int p = 0; p < SPLIT; ++p) {
    w[p] = fexp2(ml[p].x - m) * ml[p].y;
    denom += w[p];
  }
  float inv = 1.0f / denom;
  size_t idx = (size_t)r * D_ + d4;
  float4 acc;
  acc.x = 0.0f; acc.y = 0.0f; acc.z = 0.0f; acc.w = 0.0f;
  #pragma unroll
  for (int p = 0; p < SPLIT; ++p) {
    const __half2* h = reinterpret_cast<const __half2*>(PH + p * NPf + idx);
    float2 f0 = __half22float2(h[0]);
    float2 f1 = __half22float2(h[1]);
    acc.x += w[p] * f0.x; acc.y += w[p] * f0.y;
    acc.z += w[p] * f1.x; acc.w += w[p] * f1.y;
  }
  acc.x *= inv; acc.y *= inv; acc.z *= inv; acc.w *= inv;
  *reinterpret_cast<float4*>(Out + idx) = acc;
}

extern "C" void kernel_launch(void* const* d_in, const int* in_sizes, int n_in,
                              void* d_out, int out_size, void* d_ws, size_t ws_size,
                              hipStream_t stream) {
  const float* X  = (const float*)d_in[0];
  const float* Wq = (const float*)d_in[1];
  const float* Wk = (const float*)d_in[2];
  const float* Wv = (const float*)d_in[3];
  float* out = (float*)d_out;

  char* ws = (char*)d_ws;
  short* Qb = (short*)(ws);                       // 8 MB
  short* Kb = (short*)(ws + 8388608);             // 8 MB
  short* VT = (short*)(ws + 16777216);            // 8 MB (V^T, slot-permuted)
  short* WT = (short*)(ws + 25165824);            // 384 KB
  float2* ML = (float2*)(ws + 25690112);          // 512 KB (m,l per part)
  __half* PH = (__half*)(ws + 26214400);          // up to 4 x 8 MB fp16 partials
  const size_t NPh = (size_t)B_ * S_ * D_ * 2;
  const size_t need4 = 26214400 + 4 * NPh;
  const size_t need2 = 26214400 + 2 * NPh;

  wt_kernel<<<12, 256, 0, stream>>>(Wq, Wk, Wv, WT);
  proj_kernel<<<768, 256, 0, stream>>>(X, WT, Qb, Kb, VT);
  if (ws_size >= need4) {
    attn32<4><<<512, 256, 0, stream>>>(Qb, Kb, VT, out, PH, ML);
    combineN<4><<<(B_ * S_) / 4, 256, 0, stream>>>(PH, ML, out);
  } else if (ws_size >= need2) {
    attn32<2><<<256, 256, 0, stream>>>(Qb, Kb, VT, out, PH, ML);
    combineN<2><<<(B_ * S_) / 4, 256, 0, stream>>>(PH, ML, out);
  } else {
    attn32<1><<<128, 256, 0, stream>>>(Qb, Kb, VT, out, PH, (float2*)out);
  }
}